// Round 1
// baseline (734.938 us; speedup 1.0000x reference)
//
#include <hip/hip_runtime.h>
#include <hip/hip_bf16.h>
#include <cstdint>

typedef float f32x4 __attribute__((ext_vector_type(4)));
typedef short s16x8 __attribute__((ext_vector_type(8)));

constexpr int B_ = 2, L_ = 2048, D_ = 1024, H_ = 16, DH = 64, HALF = 64;
constexpr int M_ROWS = B_ * L_;   // 4096
constexpr int QKV_N = 3 * D_;     // 3072

// ---------------- RMSNorm: fp32 [row, 1024] -> bf16 ----------------
__global__ void rmsnorm_kernel(const float* __restrict__ x, const float* __restrict__ wn,
                               __hip_bfloat16* __restrict__ xn) {
    int row = blockIdx.x;
    int t = threadIdx.x;                       // 256 threads, 4 elems each
    const float4* xr = reinterpret_cast<const float4*>(x + (size_t)row * D_);
    float4 v = xr[t];
    float ss = v.x * v.x + v.y * v.y + v.z * v.z + v.w * v.w;
#pragma unroll
    for (int off = 32; off; off >>= 1) ss += __shfl_xor(ss, off);
    __shared__ float red[4];
    if ((t & 63) == 0) red[t >> 6] = ss;
    __syncthreads();
    float tot = red[0] + red[1] + red[2] + red[3];
    float rinv = rsqrtf(tot * (1.0f / D_) + 1e-6f);
    const float4* wr = reinterpret_cast<const float4*>(wn);
    float4 w = wr[t];
    __hip_bfloat16* o = xn + (size_t)row * D_ + t * 4;
    o[0] = __float2bfloat16(v.x * rinv * w.x);
    o[1] = __float2bfloat16(v.y * rinv * w.y);
    o[2] = __float2bfloat16(v.z * rinv * w.z);
    o[3] = __float2bfloat16(v.w * rinv * w.w);
}

// ---------------- fp32 -> bf16 convert (vectorized x4) ----------------
__global__ void cvt_bf16_kernel(const float* __restrict__ in, __hip_bfloat16* __restrict__ out, int n4) {
    int i = blockIdx.x * blockDim.x + threadIdx.x;
    if (i < n4) {
        float4 v = reinterpret_cast<const float4*>(in)[i];
        __hip_bfloat16* o = out + (size_t)i * 4;
        o[0] = __float2bfloat16(v.x);
        o[1] = __float2bfloat16(v.y);
        o[2] = __float2bfloat16(v.z);
        o[3] = __float2bfloat16(v.w);
    }
}

// ---------------- GEMM C[M,N] = A[M,K] * Bt[N,K]^T  (bf16 in, f32 acc) ----------------
// block: 256 thr = 4 waves (2x2), block tile 64(M) x 128(N); wave tile 32x64 = 2x4 frags of 16x16
// EPI 0: store bf16 to Cbf.  EPI 1: store f32 + residual to Cf.
template <int EPI>
__global__ void gemm_bt_kernel(const __hip_bfloat16* __restrict__ A,
                               const __hip_bfloat16* __restrict__ Bt,
                               __hip_bfloat16* __restrict__ Cbf,
                               float* __restrict__ Cf,
                               const float* __restrict__ resid,
                               int M, int N, int K) {
    int tid = threadIdx.x;
    int lane = tid & 63;
    int wid = tid >> 6;
    int waveM = wid >> 1, waveN = wid & 1;
    int rowBase = blockIdx.y * 64 + waveM * 32;
    int colBase = blockIdx.x * 128 + waveN * 64;
    int lr = lane & 15;           // A row / B col within frag
    int lk = (lane >> 4) * 8;     // k offset within frag

    f32x4 acc[2][4];
#pragma unroll
    for (int m = 0; m < 2; ++m)
#pragma unroll
        for (int n = 0; n < 4; ++n) acc[m][n] = (f32x4){0.f, 0.f, 0.f, 0.f};

    for (int k0 = 0; k0 < K; k0 += 32) {
        s16x8 a[2], b[4];
#pragma unroll
        for (int m = 0; m < 2; ++m)
            a[m] = *reinterpret_cast<const s16x8*>(A + (size_t)(rowBase + m * 16 + lr) * K + k0 + lk);
#pragma unroll
        for (int n = 0; n < 4; ++n)
            b[n] = *reinterpret_cast<const s16x8*>(Bt + (size_t)(colBase + n * 16 + lr) * K + k0 + lk);
#pragma unroll
        for (int m = 0; m < 2; ++m)
#pragma unroll
            for (int n = 0; n < 4; ++n)
                acc[m][n] = __builtin_amdgcn_mfma_f32_16x16x32_bf16(a[m], b[n], acc[m][n], 0, 0, 0);
    }

    int drow0 = (lane >> 4) * 4;
#pragma unroll
    for (int m = 0; m < 2; ++m) {
#pragma unroll
        for (int n = 0; n < 4; ++n) {
            int col = colBase + n * 16 + lr;
#pragma unroll
            for (int r = 0; r < 4; ++r) {
                int row = rowBase + m * 16 + drow0 + r;
                if (EPI == 0) {
                    Cbf[(size_t)row * N + col] = __float2bfloat16(acc[m][n][r]);
                } else {
                    Cf[(size_t)row * N + col] = acc[m][n][r] + resid[(size_t)row * N + col];
                }
            }
        }
    }
}

// ---------------- banded attention: one wave per (b,h,i), lane = dim ----------------
__global__ void attn_kernel(const __hip_bfloat16* __restrict__ qkv,
                            __hip_bfloat16* __restrict__ attn) {
    int tid = threadIdx.x;
    int lane = tid & 63;
    int gw = blockIdx.x * 4 + (tid >> 6);   // 0 .. B*H*L-1
    int i = gw & (L_ - 1);
    int bh = gw >> 11;                      // L_=2048
    int h = bh & (H_ - 1);
    int b = bh >> 4;

    const __hip_bfloat16* base = qkv + (size_t)(b * L_) * QKV_N;
    float qd = __bfloat162float(base[(size_t)i * QKV_N + h * DH + lane]) * 0.125f;

    int jlo = i - HALF; if (jlo < 0) jlo = 0;
    int jhi = i + HALF; if (jhi > L_ - 1) jhi = L_ - 1;

    float m = -3.0e38f, lsum = 0.0f, o = 0.0f;
    for (int j = jlo; j <= jhi; ++j) {
        const __hip_bfloat16* kr = base + (size_t)j * QKV_N + D_ + h * DH;
        float s = qd * __bfloat162float(kr[lane]);
#pragma unroll
        for (int off = 32; off; off >>= 1) s += __shfl_xor(s, off);
        float mn = fmaxf(m, s);
        float c = __expf(m - mn);
        float p = __expf(s - mn);
        lsum = lsum * c + p;
        float vd = __bfloat162float(kr[D_ + lane]);   // v block is D_ past k block
        o = o * c + p * vd;
        m = mn;
    }
    attn[(size_t)(b * L_ + i) * D_ + h * DH + lane] = __float2bfloat16(o / lsum);
}

extern "C" void kernel_launch(void* const* d_in, const int* in_sizes, int n_in,
                              void* d_out, int out_size, void* d_ws, size_t ws_size,
                              hipStream_t stream) {
    const float* x      = (const float*)d_in[0];
    const float* w_norm = (const float*)d_in[1];
    const float* w_qkv  = (const float*)d_in[2];
    const float* w_out  = (const float*)d_in[3];
    // d_in[4] = window_size (128), d_in[5] = n_heads (16) -- constants hard-coded.

    char* ws = (char*)d_ws;
    __hip_bfloat16* xn   = (__hip_bfloat16*)(ws);                        //  8 MiB
    __hip_bfloat16* wq   = (__hip_bfloat16*)(ws + (8u  << 20));          //  6 MiB
    __hip_bfloat16* wo   = (__hip_bfloat16*)(ws + (14u << 20));          //  2 MiB
    __hip_bfloat16* qkv  = (__hip_bfloat16*)(ws + (16u << 20));          // 24 MiB
    __hip_bfloat16* attn = (__hip_bfloat16*)(ws + (40u << 20));          //  8 MiB
    float* out = (float*)d_out;

    // weight conversions
    {
        int n4 = QKV_N * D_ / 4;
        cvt_bf16_kernel<<<(n4 + 255) / 256, 256, 0, stream>>>(w_qkv, wq, n4);
    }
    {
        int n4 = D_ * D_ / 4;
        cvt_bf16_kernel<<<(n4 + 255) / 256, 256, 0, stream>>>(w_out, wo, n4);
    }

    // RMSNorm
    rmsnorm_kernel<<<M_ROWS, 256, 0, stream>>>(x, w_norm, xn);

    // QKV GEMM: [4096,1024] x [3072,1024]^T -> bf16 [4096,3072]
    gemm_bt_kernel<0><<<dim3(QKV_N / 128, M_ROWS / 64), 256, 0, stream>>>(
        xn, wq, qkv, nullptr, nullptr, M_ROWS, QKV_N, D_);

    // banded attention -> bf16 [4096,1024]
    attn_kernel<<<(B_ * H_ * L_) / 4, 256, 0, stream>>>(qkv, attn);

    // out proj + residual: [4096,1024] x [1024,1024]^T + x -> f32 d_out
    gemm_bt_kernel<1><<<dim3(D_ / 128, M_ROWS / 64), 256, 0, stream>>>(
        attn, wo, nullptr, out, x, M_ROWS, D_, D_);
}

// Round 2
// 226.346 us; speedup vs baseline: 3.2470x; 3.2470x over previous
//
#include <hip/hip_runtime.h>
#include <hip/hip_bf16.h>
#include <cstdint>

typedef float f32x4 __attribute__((ext_vector_type(4)));
typedef short s16x8 __attribute__((ext_vector_type(8)));

constexpr int B_ = 2, L_ = 2048, D_ = 1024, H_ = 16, DH = 64, HALF = 64;
constexpr int M_ROWS = B_ * L_;   // 4096
constexpr int QKV_N = 3 * D_;     // 3072

// ---------------- RMSNorm: fp32 [row, 1024] -> bf16 ----------------
__global__ void rmsnorm_kernel(const float* __restrict__ x, const float* __restrict__ wn,
                               __hip_bfloat16* __restrict__ xn) {
    int row = blockIdx.x;
    int t = threadIdx.x;                       // 256 threads, 4 elems each
    const float4* xr = reinterpret_cast<const float4*>(x + (size_t)row * D_);
    float4 v = xr[t];
    float ss = v.x * v.x + v.y * v.y + v.z * v.z + v.w * v.w;
#pragma unroll
    for (int off = 32; off; off >>= 1) ss += __shfl_xor(ss, off);
    __shared__ float red[4];
    if ((t & 63) == 0) red[t >> 6] = ss;
    __syncthreads();
    float tot = red[0] + red[1] + red[2] + red[3];
    float rinv = rsqrtf(tot * (1.0f / D_) + 1e-6f);
    const float4* wr = reinterpret_cast<const float4*>(wn);
    float4 w = wr[t];
    __hip_bfloat16* o = xn + (size_t)row * D_ + t * 4;
    o[0] = __float2bfloat16(v.x * rinv * w.x);
    o[1] = __float2bfloat16(v.y * rinv * w.y);
    o[2] = __float2bfloat16(v.z * rinv * w.z);
    o[3] = __float2bfloat16(v.w * rinv * w.w);
}

// ---------------- fp32 -> bf16 convert (vectorized x4) ----------------
__global__ void cvt_bf16_kernel(const float* __restrict__ in, __hip_bfloat16* __restrict__ out, int n4) {
    int i = blockIdx.x * blockDim.x + threadIdx.x;
    if (i < n4) {
        float4 v = reinterpret_cast<const float4*>(in)[i];
        __hip_bfloat16* o = out + (size_t)i * 4;
        o[0] = __float2bfloat16(v.x);
        o[1] = __float2bfloat16(v.y);
        o[2] = __float2bfloat16(v.z);
        o[3] = __float2bfloat16(v.w);
    }
}

// ---------------- GEMM C[M,N] = A[M,K] * Bt[N,K]^T  (bf16 in, f32 acc) ----------------
// block: 256 thr = 4 waves (2x2), block tile 64(M) x 128(N); wave tile 32x64 = 2x4 frags of 16x16
// EPI 0: store bf16 to Cbf.  EPI 1: store f32 + residual to Cf.
template <int EPI>
__global__ void gemm_bt_kernel(const __hip_bfloat16* __restrict__ A,
                               const __hip_bfloat16* __restrict__ Bt,
                               __hip_bfloat16* __restrict__ Cbf,
                               float* __restrict__ Cf,
                               const float* __restrict__ resid,
                               int M, int N, int K) {
    int tid = threadIdx.x;
    int lane = tid & 63;
    int wid = tid >> 6;
    int waveM = wid >> 1, waveN = wid & 1;
    int rowBase = blockIdx.y * 64 + waveM * 32;
    int colBase = blockIdx.x * 128 + waveN * 64;
    int lr = lane & 15;           // A row / B col within frag
    int lk = (lane >> 4) * 8;     // k offset within frag

    f32x4 acc[2][4];
#pragma unroll
    for (int m = 0; m < 2; ++m)
#pragma unroll
        for (int n = 0; n < 4; ++n) acc[m][n] = (f32x4){0.f, 0.f, 0.f, 0.f};

    for (int k0 = 0; k0 < K; k0 += 32) {
        s16x8 a[2], b[4];
#pragma unroll
        for (int m = 0; m < 2; ++m)
            a[m] = *reinterpret_cast<const s16x8*>(A + (size_t)(rowBase + m * 16 + lr) * K + k0 + lk);
#pragma unroll
        for (int n = 0; n < 4; ++n)
            b[n] = *reinterpret_cast<const s16x8*>(Bt + (size_t)(colBase + n * 16 + lr) * K + k0 + lk);
#pragma unroll
        for (int m = 0; m < 2; ++m)
#pragma unroll
            for (int n = 0; n < 4; ++n)
                acc[m][n] = __builtin_amdgcn_mfma_f32_16x16x32_bf16(a[m], b[n], acc[m][n], 0, 0, 0);
    }

    int drow0 = (lane >> 4) * 4;
#pragma unroll
    for (int m = 0; m < 2; ++m) {
#pragma unroll
        for (int n = 0; n < 4; ++n) {
            int col = colBase + n * 16 + lr;
#pragma unroll
            for (int r = 0; r < 4; ++r) {
                int row = rowBase + m * 16 + drow0 + r;
                if (EPI == 0) {
                    Cbf[(size_t)row * N + col] = __float2bfloat16(acc[m][n][r]);
                } else {
                    Cf[(size_t)row * N + col] = acc[m][n][r] + resid[(size_t)row * N + col];
                }
            }
        }
    }
}

// ---------------- MFMA banded flash attention ----------------
// One block = 128 threads (2 waves) handles (b, h, 64 query rows).
// Wave w: q rows [q0+32w, q0+32w+32), key window jl in [32w, 32w+160) where
// jl indexes the staged K/V tile of 192 rows starting at jg0 = q0-64.
// LDS: K swizzled [192][64] (24576 B) | V^T padded [64][200] (25600 B);
// P (bf16, per wave [32][168]) aliases the K region after a barrier.
__global__ __launch_bounds__(128) void attn_mfma_kernel(const __hip_bfloat16* __restrict__ qkv,
                                                        __hip_bfloat16* __restrict__ attn) {
    __shared__ __align__(16) char smem[50176];
    constexpr int VT_OFF = 24576;
    int tid = threadIdx.x;
    int tq = blockIdx.x, h = blockIdx.y, b = blockIdx.z;
    int q0 = tq * 64;
    int jg0 = q0 - HALF;
    const __hip_bfloat16* qkvb = qkv + (size_t)(b * L_) * QKV_N;

    // ---- stage K (XOR-swizzled) and V^T ----
    {
        int r8 = tid >> 3, cs = tid & 7;
        short* Vt = (short*)(smem + VT_OFF);
#pragma unroll
        for (int seg = 0; seg < 12; ++seg) {
            int row = r8 + seg * 16;          // jl 0..191
            int jg = jg0 + row;
            int jc = jg < 0 ? 0 : (jg > L_ - 1 ? L_ - 1 : jg);
            const short* src = (const short*)(qkvb + (size_t)jc * QKV_N + D_ + h * DH + cs * 8);
            s16x8 kv = *(const s16x8*)src;
            int slot = cs ^ (row & 7);
            *(s16x8*)(smem + row * 128 + slot * 16) = kv;
            s16x8 vv = *(const s16x8*)(src + D_);   // v block is D_ past k block
#pragma unroll
            for (int e = 0; e < 8; ++e)
                Vt[(cs * 8 + e) * 200 + row] = vv[e];
        }
    }
    __syncthreads();

    int lane = tid & 63, w = tid >> 6;
    int l15 = lane & 15, hi = lane >> 4;

    // ---- Q fragments from global (L2-resident) ----
    s16x8 aq[2][2];
#pragma unroll
    for (int m = 0; m < 2; ++m)
#pragma unroll
        for (int kk = 0; kk < 2; ++kk)
            aq[m][kk] = *(const s16x8*)(qkvb + (size_t)(q0 + 32 * w + 16 * m + l15) * QKV_N
                                        + h * DH + kk * 32 + hi * 8);

    // ---- scores S = Q K^T ----
    f32x4 sc[2][10];
#pragma unroll
    for (int m = 0; m < 2; ++m)
#pragma unroll
        for (int kt = 0; kt < 10; ++kt) sc[m][kt] = (f32x4){0.f, 0.f, 0.f, 0.f};

#pragma unroll
    for (int kt = 0; kt < 10; ++kt) {
        int jl = 32 * w + 16 * kt + l15;
        s16x8 bk0 = *(const s16x8*)(smem + jl * 128 + ((hi ^ (jl & 7)) * 16));
        s16x8 bk1 = *(const s16x8*)(smem + jl * 128 + (((4 + hi) ^ (jl & 7)) * 16));
#pragma unroll
        for (int m = 0; m < 2; ++m) {
            sc[m][kt] = __builtin_amdgcn_mfma_f32_16x16x32_bf16(aq[m][0], bk0, sc[m][kt], 0, 0, 0);
            sc[m][kt] = __builtin_amdgcn_mfma_f32_16x16x32_bf16(aq[m][1], bk1, sc[m][kt], 0, 0, 0);
        }
    }

    // ---- band mask + softmax (rows split across 16-lane groups) ----
#pragma unroll
    for (int m = 0; m < 2; ++m) {
#pragma unroll
        for (int r = 0; r < 4; ++r) {
            int iloc = 32 * w + 16 * m + 4 * hi + r;
            float mx = -1e30f;
#pragma unroll
            for (int kt = 0; kt < 10; ++kt) {
                int jl = 32 * w + 16 * kt + l15;
                int jg = jg0 + jl;
                bool ok = (jl >= iloc) && (jl <= iloc + 2 * HALF) && (jg >= 0) && (jg < L_);
                float s = ok ? sc[m][kt][r] * 0.125f : -1e30f;
                sc[m][kt][r] = s;
                mx = fmaxf(mx, s);
            }
            mx = fmaxf(mx, __shfl_xor(mx, 1));
            mx = fmaxf(mx, __shfl_xor(mx, 2));
            mx = fmaxf(mx, __shfl_xor(mx, 4));
            mx = fmaxf(mx, __shfl_xor(mx, 8));
            float sum = 0.f;
#pragma unroll
            for (int kt = 0; kt < 10; ++kt) {
                float p = __expf(sc[m][kt][r] - mx);
                sc[m][kt][r] = p;
                sum += p;
            }
            sum += __shfl_xor(sum, 1);
            sum += __shfl_xor(sum, 2);
            sum += __shfl_xor(sum, 4);
            sum += __shfl_xor(sum, 8);
            float inv = 1.0f / sum;
#pragma unroll
            for (int kt = 0; kt < 10; ++kt) sc[m][kt][r] *= inv;
        }
    }

    __syncthreads();   // everyone done reading K; P aliases the K region

    // ---- write P (bf16) into per-wave LDS region ----
    {
        __hip_bfloat16* Pw = (__hip_bfloat16*)(smem + w * 10752);
#pragma unroll
        for (int m = 0; m < 2; ++m)
#pragma unroll
            for (int kt = 0; kt < 10; ++kt)
#pragma unroll
                for (int r = 0; r < 4; ++r)
                    Pw[(16 * m + 4 * hi + r) * 168 + 16 * kt + l15] = __float2bfloat16(sc[m][kt][r]);
    }
    __syncthreads();

    // ---- O = P V ----
    f32x4 o[2][4];
#pragma unroll
    for (int m = 0; m < 2; ++m)
#pragma unroll
        for (int nt = 0; nt < 4; ++nt) o[m][nt] = (f32x4){0.f, 0.f, 0.f, 0.f};

#pragma unroll
    for (int kst = 0; kst < 5; ++kst) {
        s16x8 ap[2];
#pragma unroll
        for (int m = 0; m < 2; ++m)
            ap[m] = *(const s16x8*)(smem + w * 10752 + (16 * m + l15) * 336 + (32 * kst + 8 * hi) * 2);
#pragma unroll
        for (int nt = 0; nt < 4; ++nt) {
            s16x8 bv = *(const s16x8*)(smem + VT_OFF + (16 * nt + l15) * 400
                                       + (32 * w + 32 * kst + 8 * hi) * 2);
#pragma unroll
            for (int m = 0; m < 2; ++m)
                o[m][nt] = __builtin_amdgcn_mfma_f32_16x16x32_bf16(ap[m], bv, o[m][nt], 0, 0, 0);
        }
    }

    // ---- store ----
#pragma unroll
    for (int m = 0; m < 2; ++m)
#pragma unroll
        for (int nt = 0; nt < 4; ++nt)
#pragma unroll
            for (int r = 0; r < 4; ++r) {
                int rowg = q0 + 32 * w + 16 * m + 4 * hi + r;
                attn[(size_t)(b * L_ + rowg) * D_ + h * DH + 16 * nt + l15] =
                    __float2bfloat16(o[m][nt][r]);
            }
}

extern "C" void kernel_launch(void* const* d_in, const int* in_sizes, int n_in,
                              void* d_out, int out_size, void* d_ws, size_t ws_size,
                              hipStream_t stream) {
    const float* x      = (const float*)d_in[0];
    const float* w_norm = (const float*)d_in[1];
    const float* w_qkv  = (const float*)d_in[2];
    const float* w_out  = (const float*)d_in[3];

    char* ws = (char*)d_ws;
    __hip_bfloat16* xn   = (__hip_bfloat16*)(ws);                        //  8 MiB
    __hip_bfloat16* wq   = (__hip_bfloat16*)(ws + (8u  << 20));          //  6 MiB
    __hip_bfloat16* wo   = (__hip_bfloat16*)(ws + (14u << 20));          //  2 MiB
    __hip_bfloat16* qkv  = (__hip_bfloat16*)(ws + (16u << 20));          // 24 MiB
    __hip_bfloat16* attn = (__hip_bfloat16*)(ws + (40u << 20));          //  8 MiB
    float* out = (float*)d_out;

    // weight conversions
    {
        int n4 = QKV_N * D_ / 4;
        cvt_bf16_kernel<<<(n4 + 255) / 256, 256, 0, stream>>>(w_qkv, wq, n4);
    }
    {
        int n4 = D_ * D_ / 4;
        cvt_bf16_kernel<<<(n4 + 255) / 256, 256, 0, stream>>>(w_out, wo, n4);
    }

    // RMSNorm
    rmsnorm_kernel<<<M_ROWS, 256, 0, stream>>>(x, w_norm, xn);

    // QKV GEMM: [4096,1024] x [3072,1024]^T -> bf16 [4096,3072]
    gemm_bt_kernel<0><<<dim3(QKV_N / 128, M_ROWS / 64), 256, 0, stream>>>(
        xn, wq, qkv, nullptr, nullptr, M_ROWS, QKV_N, D_);

    // MFMA banded attention -> bf16 [4096,1024]
    attn_mfma_kernel<<<dim3(L_ / 64, H_, B_), 128, 0, stream>>>(qkv, attn);

    // out proj + residual: [4096,1024] x [1024,1024]^T + x -> f32 d_out
    gemm_bt_kernel<1><<<dim3(D_ / 128, M_ROWS / 64), 256, 0, stream>>>(
        attn, wo, nullptr, out, x, M_ROWS, D_, D_);
}

// Round 3
// 113.771 us; speedup vs baseline: 6.4598x; 1.9895x over previous
//
#include <hip/hip_runtime.h>
#include <hip/hip_bf16.h>
#include <cstdint>

typedef float f32x4 __attribute__((ext_vector_type(4)));
typedef short s16x8 __attribute__((ext_vector_type(8)));

constexpr int B_ = 2, L_ = 2048, D_ = 1024, H_ = 16, DH = 64, HALF = 64;
constexpr int M_ROWS = B_ * L_;   // 4096
constexpr int QKV_N = 3 * D_;     // 3072

__device__ __forceinline__ void gload16(const void* g, void* l) {
    __builtin_amdgcn_global_load_lds(
        (const __attribute__((address_space(1))) unsigned int*)g,
        (__attribute__((address_space(3))) unsigned int*)l, 16, 0, 0);
}

// ---------------- RMSNorm: fp32 [row, 1024] -> bf16 ----------------
__global__ void rmsnorm_kernel(const float* __restrict__ x, const float* __restrict__ wn,
                               __hip_bfloat16* __restrict__ xn) {
    int row = blockIdx.x;
    int t = threadIdx.x;                       // 256 threads, 4 elems each
    const float4* xr = reinterpret_cast<const float4*>(x + (size_t)row * D_);
    float4 v = xr[t];
    float ss = v.x * v.x + v.y * v.y + v.z * v.z + v.w * v.w;
#pragma unroll
    for (int off = 32; off; off >>= 1) ss += __shfl_xor(ss, off);
    __shared__ float red[4];
    if ((t & 63) == 0) red[t >> 6] = ss;
    __syncthreads();
    float tot = red[0] + red[1] + red[2] + red[3];
    float rinv = rsqrtf(tot * (1.0f / D_) + 1e-6f);
    const float4* wr = reinterpret_cast<const float4*>(wn);
    float4 w = wr[t];
    __hip_bfloat16* o = xn + (size_t)row * D_ + t * 4;
    o[0] = __float2bfloat16(v.x * rinv * w.x);
    o[1] = __float2bfloat16(v.y * rinv * w.y);
    o[2] = __float2bfloat16(v.z * rinv * w.z);
    o[3] = __float2bfloat16(v.w * rinv * w.w);
}

// ---------------- fp32 -> bf16 convert (vectorized x4) ----------------
__global__ void cvt_bf16_kernel(const float* __restrict__ in, __hip_bfloat16* __restrict__ out, int n4) {
    int i = blockIdx.x * blockDim.x + threadIdx.x;
    if (i < n4) {
        float4 v = reinterpret_cast<const float4*>(in)[i];
        __hip_bfloat16* o = out + (size_t)i * 4;
        o[0] = __float2bfloat16(v.x);
        o[1] = __float2bfloat16(v.y);
        o[2] = __float2bfloat16(v.z);
        o[3] = __float2bfloat16(v.w);
    }
}

// ---------------- m97-style GEMM: C[M,N] = A[M,K] * Bt[N,K]^T ----------------
// 256 thr = 4 waves (2x2); block tile 128x128, BK=32; wave tile 64x64 = 4x4 frags.
// LDS: As[128][32] | Bs[128][32] bf16, staged via global_load_lds width=16.
// EPI 0: store bf16 to Cbf.  EPI 1: store f32 + residual to Cf.
template <int EPI>
__global__ __launch_bounds__(256) void gemm128_kernel(const __hip_bfloat16* __restrict__ A,
                                                      const __hip_bfloat16* __restrict__ Bt,
                                                      __hip_bfloat16* __restrict__ Cbf,
                                                      float* __restrict__ Cf,
                                                      const float* __restrict__ resid,
                                                      int M, int N, int K) {
    __shared__ __align__(16) char smem[16384];   // As: 0..8191, Bs: 8192..16383

    int tid = threadIdx.x;
    int lane = tid & 63;
    int w = tid >> 6;
    int rowBase = blockIdx.y * 128;
    int colBase = blockIdx.x * 128;

    // staging: wave w covers tile rows [32w, 32w+32) in two 1KB chunks
    int srow = 32 * w + (lane >> 2);
    int scol = (lane & 3) * 8;
    const __hip_bfloat16* aSrc = A + (size_t)(rowBase + srow) * K + scol;
    const __hip_bfloat16* bSrc = Bt + (size_t)(colBase + srow) * K + scol;
    char* aDst = smem + w * 2048;
    char* bDst = smem + 8192 + w * 2048;
    const size_t rowSkip = (size_t)16 * K;

    int waveM = w >> 1, waveN = w & 1;
    int l15 = lane & 15, hi = lane >> 4;
    const char* aRd = smem + ((64 * waveM + l15) << 6) + (hi << 4);
    const char* bRd = smem + 8192 + ((64 * waveN + l15) << 6) + (hi << 4);

    f32x4 acc[4][4];
#pragma unroll
    for (int m = 0; m < 4; ++m)
#pragma unroll
        for (int n = 0; n < 4; ++n) acc[m][n] = (f32x4){0.f, 0.f, 0.f, 0.f};

    for (int k0 = 0; k0 < K; k0 += 32) {
        gload16(aSrc + k0, aDst);
        gload16(aSrc + rowSkip + k0, aDst + 1024);
        gload16(bSrc + k0, bDst);
        gload16(bSrc + rowSkip + k0, bDst + 1024);
        __syncthreads();   // drains vmcnt(0): tiles visible

        s16x8 a[4], b[4];
#pragma unroll
        for (int m = 0; m < 4; ++m) a[m] = *(const s16x8*)(aRd + (m << 10));
#pragma unroll
        for (int n = 0; n < 4; ++n) b[n] = *(const s16x8*)(bRd + (n << 10));
#pragma unroll
        for (int m = 0; m < 4; ++m)
#pragma unroll
            for (int n = 0; n < 4; ++n)
                acc[m][n] = __builtin_amdgcn_mfma_f32_16x16x32_bf16(a[m], b[n], acc[m][n], 0, 0, 0);
        __syncthreads();   // all reads done before next stage overwrites
    }

#pragma unroll
    for (int m = 0; m < 4; ++m) {
#pragma unroll
        for (int n = 0; n < 4; ++n) {
            int col = colBase + 64 * waveN + n * 16 + l15;
#pragma unroll
            for (int r = 0; r < 4; ++r) {
                int row = rowBase + 64 * waveM + m * 16 + 4 * hi + r;
                if (EPI == 0) {
                    Cbf[(size_t)row * N + col] = __float2bfloat16(acc[m][n][r]);
                } else {
                    Cf[(size_t)row * N + col] = acc[m][n][r] + resid[(size_t)row * N + col];
                }
            }
        }
    }
}

// ---------------- MFMA banded flash attention ----------------
// One block = 128 threads (2 waves) handles (b, h, 64 query rows).
__global__ __launch_bounds__(128) void attn_mfma_kernel(const __hip_bfloat16* __restrict__ qkv,
                                                        __hip_bfloat16* __restrict__ attn) {
    __shared__ __align__(16) char smem[50176];
    constexpr int VT_OFF = 24576;
    int tid = threadIdx.x;
    int tq = blockIdx.x, h = blockIdx.y, b = blockIdx.z;
    int q0 = tq * 64;
    int jg0 = q0 - HALF;
    const __hip_bfloat16* qkvb = qkv + (size_t)(b * L_) * QKV_N;

    // ---- stage K (XOR-swizzled) and V^T ----
    {
        int r8 = tid >> 3, cs = tid & 7;
        short* Vt = (short*)(smem + VT_OFF);
#pragma unroll
        for (int seg = 0; seg < 12; ++seg) {
            int row = r8 + seg * 16;          // jl 0..191
            int jg = jg0 + row;
            int jc = jg < 0 ? 0 : (jg > L_ - 1 ? L_ - 1 : jg);
            const short* src = (const short*)(qkvb + (size_t)jc * QKV_N + D_ + h * DH + cs * 8);
            s16x8 kv = *(const s16x8*)src;
            int slot = cs ^ (row & 7);
            *(s16x8*)(smem + row * 128 + slot * 16) = kv;
            s16x8 vv = *(const s16x8*)(src + D_);   // v block is D_ past k block
#pragma unroll
            for (int e = 0; e < 8; ++e)
                Vt[(cs * 8 + e) * 200 + row] = vv[e];
        }
    }
    __syncthreads();

    int lane = tid & 63, w = tid >> 6;
    int l15 = lane & 15, hi = lane >> 4;

    // ---- Q fragments from global (L2-resident) ----
    s16x8 aq[2][2];
#pragma unroll
    for (int m = 0; m < 2; ++m)
#pragma unroll
        for (int kk = 0; kk < 2; ++kk)
            aq[m][kk] = *(const s16x8*)(qkvb + (size_t)(q0 + 32 * w + 16 * m + l15) * QKV_N
                                        + h * DH + kk * 32 + hi * 8);

    // ---- scores S = Q K^T ----
    f32x4 sc[2][10];
#pragma unroll
    for (int m = 0; m < 2; ++m)
#pragma unroll
        for (int kt = 0; kt < 10; ++kt) sc[m][kt] = (f32x4){0.f, 0.f, 0.f, 0.f};

#pragma unroll
    for (int kt = 0; kt < 10; ++kt) {
        int jl = 32 * w + 16 * kt + l15;
        s16x8 bk0 = *(const s16x8*)(smem + jl * 128 + ((hi ^ (jl & 7)) * 16));
        s16x8 bk1 = *(const s16x8*)(smem + jl * 128 + (((4 + hi) ^ (jl & 7)) * 16));
#pragma unroll
        for (int m = 0; m < 2; ++m) {
            sc[m][kt] = __builtin_amdgcn_mfma_f32_16x16x32_bf16(aq[m][0], bk0, sc[m][kt], 0, 0, 0);
            sc[m][kt] = __builtin_amdgcn_mfma_f32_16x16x32_bf16(aq[m][1], bk1, sc[m][kt], 0, 0, 0);
        }
    }

    // ---- band mask + softmax (rows split across 16-lane groups) ----
#pragma unroll
    for (int m = 0; m < 2; ++m) {
#pragma unroll
        for (int r = 0; r < 4; ++r) {
            int iloc = 32 * w + 16 * m + 4 * hi + r;
            float mx = -1e30f;
#pragma unroll
            for (int kt = 0; kt < 10; ++kt) {
                int jl = 32 * w + 16 * kt + l15;
                int jg = jg0 + jl;
                bool ok = (jl >= iloc) && (jl <= iloc + 2 * HALF) && (jg >= 0) && (jg < L_);
                float s = ok ? sc[m][kt][r] * 0.125f : -1e30f;
                sc[m][kt][r] = s;
                mx = fmaxf(mx, s);
            }
            mx = fmaxf(mx, __shfl_xor(mx, 1));
            mx = fmaxf(mx, __shfl_xor(mx, 2));
            mx = fmaxf(mx, __shfl_xor(mx, 4));
            mx = fmaxf(mx, __shfl_xor(mx, 8));
            float sum = 0.f;
#pragma unroll
            for (int kt = 0; kt < 10; ++kt) {
                float p = __expf(sc[m][kt][r] - mx);
                sc[m][kt][r] = p;
                sum += p;
            }
            sum += __shfl_xor(sum, 1);
            sum += __shfl_xor(sum, 2);
            sum += __shfl_xor(sum, 4);
            sum += __shfl_xor(sum, 8);
            float inv = 1.0f / sum;
#pragma unroll
            for (int kt = 0; kt < 10; ++kt) sc[m][kt][r] *= inv;
        }
    }

    __syncthreads();   // everyone done reading K; P aliases the K region

    // ---- write P (bf16) into per-wave LDS region ----
    {
        __hip_bfloat16* Pw = (__hip_bfloat16*)(smem + w * 10752);
#pragma unroll
        for (int m = 0; m < 2; ++m)
#pragma unroll
            for (int kt = 0; kt < 10; ++kt)
#pragma unroll
                for (int r = 0; r < 4; ++r)
                    Pw[(16 * m + 4 * hi + r) * 168 + 16 * kt + l15] = __float2bfloat16(sc[m][kt][r]);
    }
    __syncthreads();

    // ---- O = P V ----
    f32x4 o[2][4];
#pragma unroll
    for (int m = 0; m < 2; ++m)
#pragma unroll
        for (int nt = 0; nt < 4; ++nt) o[m][nt] = (f32x4){0.f, 0.f, 0.f, 0.f};

#pragma unroll
    for (int kst = 0; kst < 5; ++kst) {
        s16x8 ap[2];
#pragma unroll
        for (int m = 0; m < 2; ++m)
            ap[m] = *(const s16x8*)(smem + w * 10752 + (16 * m + l15) * 336 + (32 * kst + 8 * hi) * 2);
#pragma unroll
        for (int nt = 0; nt < 4; ++nt) {
            s16x8 bv = *(const s16x8*)(smem + VT_OFF + (16 * nt + l15) * 400
                                       + (32 * w + 32 * kst + 8 * hi) * 2);
#pragma unroll
            for (int m = 0; m < 2; ++m)
                o[m][nt] = __builtin_amdgcn_mfma_f32_16x16x32_bf16(ap[m], bv, o[m][nt], 0, 0, 0);
        }
    }

    // ---- store ----
#pragma unroll
    for (int m = 0; m < 2; ++m)
#pragma unroll
        for (int nt = 0; nt < 4; ++nt)
#pragma unroll
            for (int r = 0; r < 4; ++r) {
                int rowg = q0 + 32 * w + 16 * m + 4 * hi + r;
                attn[(size_t)(b * L_ + rowg) * D_ + h * DH + 16 * nt + l15] =
                    __float2bfloat16(o[m][nt][r]);
            }
}

extern "C" void kernel_launch(void* const* d_in, const int* in_sizes, int n_in,
                              void* d_out, int out_size, void* d_ws, size_t ws_size,
                              hipStream_t stream) {
    const float* x      = (const float*)d_in[0];
    const float* w_norm = (const float*)d_in[1];
    const float* w_qkv  = (const float*)d_in[2];
    const float* w_out  = (const float*)d_in[3];

    char* ws = (char*)d_ws;
    __hip_bfloat16* xn   = (__hip_bfloat16*)(ws);                        //  8 MiB
    __hip_bfloat16* wq   = (__hip_bfloat16*)(ws + (8u  << 20));          //  6 MiB
    __hip_bfloat16* wo   = (__hip_bfloat16*)(ws + (14u << 20));          //  2 MiB
    __hip_bfloat16* qkv  = (__hip_bfloat16*)(ws + (16u << 20));          // 24 MiB
    __hip_bfloat16* attn = (__hip_bfloat16*)(ws + (40u << 20));          //  8 MiB
    float* out = (float*)d_out;

    // weight conversions
    {
        int n4 = QKV_N * D_ / 4;
        cvt_bf16_kernel<<<(n4 + 255) / 256, 256, 0, stream>>>(w_qkv, wq, n4);
    }
    {
        int n4 = D_ * D_ / 4;
        cvt_bf16_kernel<<<(n4 + 255) / 256, 256, 0, stream>>>(w_out, wo, n4);
    }

    // RMSNorm
    rmsnorm_kernel<<<M_ROWS, 256, 0, stream>>>(x, w_norm, xn);

    // QKV GEMM: [4096,1024] x [3072,1024]^T -> bf16 [4096,3072]
    gemm128_kernel<0><<<dim3(QKV_N / 128, M_ROWS / 128), 256, 0, stream>>>(
        xn, wq, qkv, nullptr, nullptr, M_ROWS, QKV_N, D_);

    // MFMA banded attention -> bf16 [4096,1024]
    attn_mfma_kernel<<<dim3(L_ / 64, H_, B_), 128, 0, stream>>>(qkv, attn);

    // out proj + residual: [4096,1024] x [1024,1024]^T + x -> f32 d_out
    gemm128_kernel<1><<<dim3(D_ / 128, M_ROWS / 128), 256, 0, stream>>>(
        attn, wo, nullptr, out, x, M_ROWS, D_, D_);
}

// Round 4
// 91.881 us; speedup vs baseline: 7.9988x; 1.2382x over previous
//
#include <hip/hip_runtime.h>
#include <hip/hip_bf16.h>
#include <cstdint>

typedef float f32x4 __attribute__((ext_vector_type(4)));
typedef short s16x8 __attribute__((ext_vector_type(8)));

constexpr int B_ = 2, L_ = 2048, D_ = 1024, H_ = 16, DH = 64, HALF = 64;
constexpr int M_ROWS = B_ * L_;   // 4096
constexpr int QKV_N = 3 * D_;     // 3072

__device__ __forceinline__ void gload16(const void* g, void* l) {
    __builtin_amdgcn_global_load_lds(
        (const __attribute__((address_space(1))) unsigned int*)g,
        (__attribute__((address_space(3))) unsigned int*)l, 16, 0, 0);
}

// ---------------- RMSNorm: fp32 [row, 1024] -> bf16 ----------------
__global__ void rmsnorm_kernel(const float* __restrict__ x, const float* __restrict__ wn,
                               __hip_bfloat16* __restrict__ xn) {
    int row = blockIdx.x;
    int t = threadIdx.x;                       // 256 threads, 4 elems each
    const float4* xr = reinterpret_cast<const float4*>(x + (size_t)row * D_);
    float4 v = xr[t];
    float ss = v.x * v.x + v.y * v.y + v.z * v.z + v.w * v.w;
#pragma unroll
    for (int off = 32; off; off >>= 1) ss += __shfl_xor(ss, off);
    __shared__ float red[4];
    if ((t & 63) == 0) red[t >> 6] = ss;
    __syncthreads();
    float tot = red[0] + red[1] + red[2] + red[3];
    float rinv = rsqrtf(tot * (1.0f / D_) + 1e-6f);
    const float4* wr = reinterpret_cast<const float4*>(wn);
    float4 w = wr[t];
    __hip_bfloat16* o = xn + (size_t)row * D_ + t * 4;
    o[0] = __float2bfloat16(v.x * rinv * w.x);
    o[1] = __float2bfloat16(v.y * rinv * w.y);
    o[2] = __float2bfloat16(v.z * rinv * w.z);
    o[3] = __float2bfloat16(v.w * rinv * w.w);
}

// ---------------- fused fp32 -> bf16 convert of both weights ----------------
__global__ void cvt_weights_kernel(const float* __restrict__ wq, const float* __restrict__ wo,
                                   __hip_bfloat16* __restrict__ oq, __hip_bfloat16* __restrict__ oo) {
    constexpr int NQ4 = QKV_N * D_ / 4;        // 786432
    int i = blockIdx.x * blockDim.x + threadIdx.x;   // 0 .. NQ4 + D_*D_/4 - 1
    const float* src; __hip_bfloat16* dst; int j;
    if (i < NQ4) { src = wq; dst = oq; j = i; }
    else         { src = wo; dst = oo; j = i - NQ4; }
    float4 v = reinterpret_cast<const float4*>(src)[j];
    __hip_bfloat16* o = dst + (size_t)j * 4;
    o[0] = __float2bfloat16(v.x);
    o[1] = __float2bfloat16(v.y);
    o[2] = __float2bfloat16(v.z);
    o[3] = __float2bfloat16(v.w);
}

// ---------------- pipelined GEMM: C[M,N] = A[M,K] * Bt[N,K]^T ----------------
// 256 thr = 4 waves (2x2); block tile 128x128, BK=64; wave tile 64x64 = 4x4 frags.
// 2 LDS buffers of (A 128x64 + B 128x64) bf16 = 32 KB each, 64 KB total.
// Counted-vmcnt pipeline: raw s_barrier (no waitcnt drain); per K-tile:
//   barrier -> issue 8 gload_lds for tile kt+1 into buf^1 -> s_waitcnt vmcnt(8)
//   (tile kt landed, kt+1 still in flight) -> ds_read frags -> 32 MFMA.
// LDS XOR swizzle (slot ^= row&7) applied via inverse-swizzled GLOBAL source
// (gload_lds dest is linear) + swizzled ds_read address.
// EPI 0: store bf16 to Cbf.  EPI 1: store f32 + residual to Cf.
template <int EPI>
__global__ __launch_bounds__(256, 2) void gemm_pipe_kernel(const __hip_bfloat16* __restrict__ A,
                                                           const __hip_bfloat16* __restrict__ Bt,
                                                           __hip_bfloat16* __restrict__ Cbf,
                                                           float* __restrict__ Cf,
                                                           const float* __restrict__ resid,
                                                           int M, int N, int K) {
    constexpr int BM = 128, BN = 128;
    constexpr int BUF = (BM + BN) * 128;       // 32 KB per buffer
    __shared__ __align__(16) char smem[2 * BUF];

    const int tid = threadIdx.x;
    const int lane = tid & 63;
    const int wid = tid >> 6;

    // ---- XCD-aware bijective block swizzle (nwg % 8 == 0 for both grids) ----
    int nwg = gridDim.x * gridDim.y;
    int lin = blockIdx.y * gridDim.x + blockIdx.x;
    int cpx = nwg >> 3;
    int swz = (lin & 7) * cpx + (lin >> 3);
    int bx = swz % gridDim.x;
    int by = swz / gridDim.x;

    const int rowBase = by * BM;
    const int colBase = bx * BN;
    const int NTILES = K >> 6;

    // ---- staging: thread t covers (row = t>>3 [+32 per issue], slot q = t&7) ----
    // LDS slot s holds global column ((s&7) ^ (row&7)); reads XOR the same way.
    const int srow = tid >> 3;                  // 0..31
    const int colSw = ((tid & 7) ^ (srow & 7)) << 3;   // element offset, mult of 8
    const __hip_bfloat16* aG = A + (size_t)(rowBase + srow) * K + colSw;
    const __hip_bfloat16* bG = Bt + (size_t)(colBase + srow) * K + colSw;
    const int dstW = wid << 10;                 // wid*1024 bytes (wave-uniform)

    // ---- fragment read coords ----
    const int wm = wid >> 1, wn = wid & 1;
    const int l15 = lane & 15, hi = lane >> 4;
    const int s7 = l15 & 7;
    const int rA = wm * 64 + l15;
    const int rB = wn * 64 + l15;

    f32x4 acc[4][4];
#pragma unroll
    for (int m = 0; m < 4; ++m)
#pragma unroll
        for (int n = 0; n < 4; ++n) acc[m][n] = (f32x4){0.f, 0.f, 0.f, 0.f};

    // prologue: stage tile 0 into buf 0
    {
        const __hip_bfloat16* as = aG;
        const __hip_bfloat16* bs = bG;
#pragma unroll
        for (int i = 0; i < 4; ++i) {
            gload16(as + (size_t)(i * 32) * K, smem + i * 4096 + dstW);
            gload16(bs + (size_t)(i * 32) * K, smem + BM * 128 + i * 4096 + dstW);
        }
    }

    for (int kt = 0; kt < NTILES; ++kt) {
        const int bf = kt & 1;
        __builtin_amdgcn_s_barrier();           // all waves done reading buf bf^1
        if (kt + 1 < NTILES) {
            char* base = smem + (bf ^ 1) * BUF;
            const __hip_bfloat16* as = aG + (size_t)(kt + 1) * 64;
            const __hip_bfloat16* bs = bG + (size_t)(kt + 1) * 64;
#pragma unroll
            for (int i = 0; i < 4; ++i) {
                gload16(as + (size_t)(i * 32) * K, base + i * 4096 + dstW);
                gload16(bs + (size_t)(i * 32) * K, base + BM * 128 + i * 4096 + dstW);
            }
            asm volatile("s_waitcnt vmcnt(8)" ::: "memory");   // tile kt landed
        } else {
            asm volatile("s_waitcnt vmcnt(0)" ::: "memory");
        }

        const char* ab = smem + bf * BUF;
        const char* bb = ab + BM * 128;
        s16x8 af[4][2], bfr[4][2];
#pragma unroll
        for (int mf = 0; mf < 4; ++mf)
#pragma unroll
            for (int kk = 0; kk < 2; ++kk)
                af[mf][kk] = *(const s16x8*)(ab + (rA + mf * 16) * 128 + (((kk * 4 + hi) ^ s7) << 4));
#pragma unroll
        for (int nf = 0; nf < 4; ++nf)
#pragma unroll
            for (int kk = 0; kk < 2; ++kk)
                bfr[nf][kk] = *(const s16x8*)(bb + (rB + nf * 16) * 128 + (((kk * 4 + hi) ^ s7) << 4));

        __builtin_amdgcn_s_setprio(1);
#pragma unroll
        for (int kk = 0; kk < 2; ++kk)
#pragma unroll
            for (int mf = 0; mf < 4; ++mf)
#pragma unroll
                for (int nf = 0; nf < 4; ++nf)
                    acc[mf][nf] = __builtin_amdgcn_mfma_f32_16x16x32_bf16(af[mf][kk], bfr[nf][kk],
                                                                          acc[mf][nf], 0, 0, 0);
        __builtin_amdgcn_s_setprio(0);
    }

#pragma unroll
    for (int mf = 0; mf < 4; ++mf) {
#pragma unroll
        for (int nf = 0; nf < 4; ++nf) {
            int col = colBase + wn * 64 + nf * 16 + l15;
#pragma unroll
            for (int r = 0; r < 4; ++r) {
                int row = rowBase + wm * 64 + mf * 16 + 4 * hi + r;
                if (EPI == 0) {
                    Cbf[(size_t)row * N + col] = __float2bfloat16(acc[mf][nf][r]);
                } else {
                    Cf[(size_t)row * N + col] = acc[mf][nf][r] + resid[(size_t)row * N + col];
                }
            }
        }
    }
}

// ---------------- MFMA banded flash attention ----------------
// One block = 128 threads (2 waves) handles (b, h, 64 query rows).
__global__ __launch_bounds__(128) void attn_mfma_kernel(const __hip_bfloat16* __restrict__ qkv,
                                                        __hip_bfloat16* __restrict__ attn) {
    __shared__ __align__(16) char smem[50176];
    constexpr int VT_OFF = 24576;
    int tid = threadIdx.x;
    int tq = blockIdx.x, h = blockIdx.y, b = blockIdx.z;
    int q0 = tq * 64;
    int jg0 = q0 - HALF;
    const __hip_bfloat16* qkvb = qkv + (size_t)(b * L_) * QKV_N;

    // ---- stage K (XOR-swizzled) and V^T ----
    {
        int r8 = tid >> 3, cs = tid & 7;
        short* Vt = (short*)(smem + VT_OFF);
#pragma unroll
        for (int seg = 0; seg < 12; ++seg) {
            int row = r8 + seg * 16;          // jl 0..191
            int jg = jg0 + row;
            int jc = jg < 0 ? 0 : (jg > L_ - 1 ? L_ - 1 : jg);
            const short* src = (const short*)(qkvb + (size_t)jc * QKV_N + D_ + h * DH + cs * 8);
            s16x8 kv = *(const s16x8*)src;
            int slot = cs ^ (row & 7);
            *(s16x8*)(smem + row * 128 + slot * 16) = kv;
            s16x8 vv = *(const s16x8*)(src + D_);   // v block is D_ past k block
#pragma unroll
            for (int e = 0; e < 8; ++e)
                Vt[(cs * 8 + e) * 200 + row] = vv[e];
        }
    }
    __syncthreads();

    int lane = tid & 63, w = tid >> 6;
    int l15 = lane & 15, hi = lane >> 4;

    // ---- Q fragments from global (L2-resident) ----
    s16x8 aq[2][2];
#pragma unroll
    for (int m = 0; m < 2; ++m)
#pragma unroll
        for (int kk = 0; kk < 2; ++kk)
            aq[m][kk] = *(const s16x8*)(qkvb + (size_t)(q0 + 32 * w + 16 * m + l15) * QKV_N
                                        + h * DH + kk * 32 + hi * 8);

    // ---- scores S = Q K^T ----
    f32x4 sc[2][10];
#pragma unroll
    for (int m = 0; m < 2; ++m)
#pragma unroll
        for (int kt = 0; kt < 10; ++kt) sc[m][kt] = (f32x4){0.f, 0.f, 0.f, 0.f};

#pragma unroll
    for (int kt = 0; kt < 10; ++kt) {
        int jl = 32 * w + 16 * kt + l15;
        s16x8 bk0 = *(const s16x8*)(smem + jl * 128 + ((hi ^ (jl & 7)) * 16));
        s16x8 bk1 = *(const s16x8*)(smem + jl * 128 + (((4 + hi) ^ (jl & 7)) * 16));
#pragma unroll
        for (int m = 0; m < 2; ++m) {
            sc[m][kt] = __builtin_amdgcn_mfma_f32_16x16x32_bf16(aq[m][0], bk0, sc[m][kt], 0, 0, 0);
            sc[m][kt] = __builtin_amdgcn_mfma_f32_16x16x32_bf16(aq[m][1], bk1, sc[m][kt], 0, 0, 0);
        }
    }

    // ---- band mask + softmax (rows split across 16-lane groups) ----
#pragma unroll
    for (int m = 0; m < 2; ++m) {
#pragma unroll
        for (int r = 0; r < 4; ++r) {
            int iloc = 32 * w + 16 * m + 4 * hi + r;
            float mx = -1e30f;
#pragma unroll
            for (int kt = 0; kt < 10; ++kt) {
                int jl = 32 * w + 16 * kt + l15;
                int jg = jg0 + jl;
                bool ok = (jl >= iloc) && (jl <= iloc + 2 * HALF) && (jg >= 0) && (jg < L_);
                float s = ok ? sc[m][kt][r] * 0.125f : -1e30f;
                sc[m][kt][r] = s;
                mx = fmaxf(mx, s);
            }
            mx = fmaxf(mx, __shfl_xor(mx, 1));
            mx = fmaxf(mx, __shfl_xor(mx, 2));
            mx = fmaxf(mx, __shfl_xor(mx, 4));
            mx = fmaxf(mx, __shfl_xor(mx, 8));
            float sum = 0.f;
#pragma unroll
            for (int kt = 0; kt < 10; ++kt) {
                float p = __expf(sc[m][kt][r] - mx);
                sc[m][kt][r] = p;
                sum += p;
            }
            sum += __shfl_xor(sum, 1);
            sum += __shfl_xor(sum, 2);
            sum += __shfl_xor(sum, 4);
            sum += __shfl_xor(sum, 8);
            float inv = 1.0f / sum;
#pragma unroll
            for (int kt = 0; kt < 10; ++kt) sc[m][kt][r] *= inv;
        }
    }

    __syncthreads();   // everyone done reading K; P aliases the K region

    // ---- write P (bf16) into per-wave LDS region ----
    {
        __hip_bfloat16* Pw = (__hip_bfloat16*)(smem + w * 10752);
#pragma unroll
        for (int m = 0; m < 2; ++m)
#pragma unroll
            for (int kt = 0; kt < 10; ++kt)
#pragma unroll
                for (int r = 0; r < 4; ++r)
                    Pw[(16 * m + 4 * hi + r) * 168 + 16 * kt + l15] = __float2bfloat16(sc[m][kt][r]);
    }
    __syncthreads();

    // ---- O = P V ----
    f32x4 o[2][4];
#pragma unroll
    for (int m = 0; m < 2; ++m)
#pragma unroll
        for (int nt = 0; nt < 4; ++nt) o[m][nt] = (f32x4){0.f, 0.f, 0.f, 0.f};

#pragma unroll
    for (int kst = 0; kst < 5; ++kst) {
        s16x8 ap[2];
#pragma unroll
        for (int m = 0; m < 2; ++m)
            ap[m] = *(const s16x8*)(smem + w * 10752 + (16 * m + l15) * 336 + (32 * kst + 8 * hi) * 2);
#pragma unroll
        for (int nt = 0; nt < 4; ++nt) {
            s16x8 bv = *(const s16x8*)(smem + VT_OFF + (16 * nt + l15) * 400
                                       + (32 * w + 32 * kst + 8 * hi) * 2);
#pragma unroll
            for (int m = 0; m < 2; ++m)
                o[m][nt] = __builtin_amdgcn_mfma_f32_16x16x32_bf16(ap[m], bv, o[m][nt], 0, 0, 0);
        }
    }

    // ---- store ----
#pragma unroll
    for (int m = 0; m < 2; ++m)
#pragma unroll
        for (int nt = 0; nt < 4; ++nt)
#pragma unroll
            for (int r = 0; r < 4; ++r) {
                int rowg = q0 + 32 * w + 16 * m + 4 * hi + r;
                attn[(size_t)(b * L_ + rowg) * D_ + h * DH + 16 * nt + l15] =
                    __float2bfloat16(o[m][nt][r]);
            }
}

extern "C" void kernel_launch(void* const* d_in, const int* in_sizes, int n_in,
                              void* d_out, int out_size, void* d_ws, size_t ws_size,
                              hipStream_t stream) {
    const float* x      = (const float*)d_in[0];
    const float* w_norm = (const float*)d_in[1];
    const float* w_qkv  = (const float*)d_in[2];
    const float* w_out  = (const float*)d_in[3];

    char* ws = (char*)d_ws;
    __hip_bfloat16* xn   = (__hip_bfloat16*)(ws);                        //  8 MiB
    __hip_bfloat16* wq   = (__hip_bfloat16*)(ws + (8u  << 20));          //  6 MiB
    __hip_bfloat16* wo   = (__hip_bfloat16*)(ws + (14u << 20));          //  2 MiB
    __hip_bfloat16* qkv  = (__hip_bfloat16*)(ws + (16u << 20));          // 24 MiB
    __hip_bfloat16* attn = (__hip_bfloat16*)(ws + (40u << 20));          //  8 MiB
    float* out = (float*)d_out;

    // fused weight conversion (wq then wo)
    {
        int n4 = (QKV_N * D_ + D_ * D_) / 4;
        cvt_weights_kernel<<<n4 / 256, 256, 0, stream>>>(w_qkv, w_out, wq, wo);
    }

    // RMSNorm
    rmsnorm_kernel<<<M_ROWS, 256, 0, stream>>>(x, w_norm, xn);

    // QKV GEMM: [4096,1024] x [3072,1024]^T -> bf16 [4096,3072]
    gemm_pipe_kernel<0><<<dim3(QKV_N / 128, M_ROWS / 128), 256, 0, stream>>>(
        xn, wq, qkv, nullptr, nullptr, M_ROWS, QKV_N, D_);

    // MFMA banded attention -> bf16 [4096,1024]
    attn_mfma_kernel<<<dim3(L_ / 64, H_, B_), 128, 0, stream>>>(qkv, attn);

    // out proj + residual: [4096,1024] x [1024,1024]^T + x -> f32 d_out
    gemm_pipe_kernel<1><<<dim3(D_ / 128, M_ROWS / 128), 256, 0, stream>>>(
        attn, wo, nullptr, out, x, M_ROWS, D_, D_);
}